// Round 12
// baseline (1641.126 us; speedup 1.0000x reference)
//
#include <hip/hip_runtime.h>
#include <hip/hip_bf16.h>

// Problem constants (reference: B=2,S=2048 -> T=4096; H=1024, I=4096, E=8, 2 steps)
#define T_TOK 4096
#define H_DIM 1024
#define I_DIM 4096
#define E_EXP 8
#define RMS_EPS_F 1e-6f

using bf16x8 = __attribute__((ext_vector_type(8))) __bf16;
using f32x4  = __attribute__((ext_vector_type(4))) float;

__device__ inline void gload_lds16(const void* g, void* l) {
    __builtin_amdgcn_global_load_lds(
        (const __attribute__((address_space(1))) void*)g,
        (__attribute__((address_space(3))) void*)l,
        16, 0, 0);
}

// -------- transpose + fp32->bf16 convert: in [R][C] -> out [C][R], batched over blockIdx.z
__global__ __launch_bounds__(256) void k_transpose_cvt(
    const float* __restrict__ in, __hip_bfloat16* __restrict__ out, int R, int C)
{
    __shared__ float tile[32][33];
    const size_t mat = (size_t)R * C;
    in  += (size_t)blockIdx.z * mat;
    out += (size_t)blockIdx.z * mat;
    const int c0 = blockIdx.x * 32, r0 = blockIdx.y * 32;
    const int tx = threadIdx.x & 31, ty = threadIdx.x >> 5;   // 32 x 8
#pragma unroll
    for (int dy = 0; dy < 32; dy += 8)
        tile[ty + dy][tx] = in[(size_t)(r0 + ty + dy) * C + (c0 + tx)];
    __syncthreads();
#pragma unroll
    for (int dy = 0; dy < 32; dy += 8)
        out[(size_t)(c0 + ty + dy) * R + (r0 + tx)] = __float2bfloat16(tile[tx][ty + dy]);
}

// -------- token prep: x [T,H] fp32 -> tb [T,H] bf16, optional rmsnorm*ln_w. 1 block/token.
__global__ __launch_bounds__(256) void k_prep(
    const float* __restrict__ x, const float* __restrict__ lnw,
    __hip_bfloat16* __restrict__ tb, int do_norm)
{
    const int t = blockIdx.x;
    const float* row = x + (size_t)t * H_DIM;
    const int base = threadIdx.x * 4;
    float4 v = *(const float4*)(row + base);
    if (do_norm) {
        float ss = v.x*v.x + v.y*v.y + v.z*v.z + v.w*v.w;
#pragma unroll
        for (int off = 32; off > 0; off >>= 1) ss += __shfl_xor(ss, off);
        __shared__ float wsum[4];
        const int w = threadIdx.x >> 6;
        if ((threadIdx.x & 63) == 0) wsum[w] = ss;
        __syncthreads();
        const float tot = wsum[0] + wsum[1] + wsum[2] + wsum[3];
        const float scale = rsqrtf(tot * (1.0f / H_DIM) + RMS_EPS_F);
        float4 g = *(const float4*)(lnw + base);
        v.x *= scale * g.x; v.y *= scale * g.y; v.z *= scale * g.z; v.w *= scale * g.w;
    }
    __hip_bfloat16* o = tb + (size_t)t * H_DIM + base;
    o[0] = __float2bfloat16(v.x); o[1] = __float2bfloat16(v.y);
    o[2] = __float2bfloat16(v.z); o[3] = __float2bfloat16(v.w);
}

// -------- gate: logits = tb @ gate_w^T, softmax over E=8. One wave per token.
__global__ __launch_bounds__(256) void k_gate(
    const __hip_bfloat16* __restrict__ tb, const float* __restrict__ gw,
    float* __restrict__ rw)
{
    const int t = blockIdx.x * 4 + (threadIdx.x >> 6);
    const int lane = threadIdx.x & 63;
    const __hip_bfloat16* row = tb + (size_t)t * H_DIM;
    float acc[E_EXP];
#pragma unroll
    for (int e = 0; e < E_EXP; ++e) acc[e] = 0.f;
    for (int h = lane; h < H_DIM; h += 64) {
        const float xv = __bfloat162float(row[h]);
#pragma unroll
        for (int e = 0; e < E_EXP; ++e) acc[e] += xv * gw[e * H_DIM + h];
    }
#pragma unroll
    for (int e = 0; e < E_EXP; ++e) {
#pragma unroll
        for (int off = 32; off > 0; off >>= 1) acc[e] += __shfl_xor(acc[e], off);
    }
    if (lane == 0) {
        float mx = acc[0];
#pragma unroll
        for (int e = 1; e < E_EXP; ++e) mx = fmaxf(mx, acc[e]);
        float ex[E_EXP], s = 0.f;
#pragma unroll
        for (int e = 0; e < E_EXP; ++e) { ex[e] = __expf(acc[e] - mx); s += ex[e]; }
        const float inv = 1.f / s;
#pragma unroll
        for (int e = 0; e < E_EXP; ++e) rw[(size_t)t * E_EXP + e] = ex[e] * inv;
    }
}

// ======== 128x128 GEMM, 4 waves (2x2), 64x64 per wave, BK=64 dbuf, 64KB LDS
//          -> 2 RESIDENT BLOCKS/CU (round-9 kernel, validated: VGPR 88, 0
//          conflicts, no spill). Round-12 changes vs R9:
//   (a) grid x = M-TILES: 32 consecutive blocks share one B weight panel
//       (L2-resident) instead of refetching it per m-group — R9's measured
//       failure was FETCH=540MB of B refetch (x was n-fastest). A (tb/hb[z])
//       is L3-hot across its n-passes since z is dispatch-outermost.
//   (b) rw folded into MODE 0 epilogue (GEMM2 linear in hb) — R11-validated.
//   (c) MODE 2 writes eo in bf16 — R11-validated.
// Sync ledger identical to R9: stage(t+1 -> buf^1) while reading buf; one
// vmcnt(0) + one barrier per K-tile. T2 swizzle involution unchanged.

__device__ __forceinline__ void ld4(bf16x8 (&r)[4], const char* rd, int kof) {
#pragma unroll
    for (int i = 0; i < 4; ++i)
        r[i] = *(const bf16x8*)(rd + i * 2048 + kof);
}
__device__ __forceinline__ void mfma16(const bf16x8 (&a)[4], const bf16x8 (&b)[4],
                                       f32x4 (&acc)[4][4]) {
    __builtin_amdgcn_s_setprio(1);
#pragma unroll
    for (int mi = 0; mi < 4; ++mi)
#pragma unroll
        for (int ni = 0; ni < 4; ++ni)
            acc[mi][ni] = __builtin_amdgcn_mfma_f32_16x16x32_bf16(
                a[mi], b[ni], acc[mi][ni], 0, 0, 0);
    __builtin_amdgcn_s_setprio(0);
}

#define BAR()   __builtin_amdgcn_s_barrier()
#define LGKM0() asm volatile("s_waitcnt lgkmcnt(0)" ::: "memory")
#define VMW0()  asm volatile("s_waitcnt vmcnt(0)" ::: "memory")
#define SCHED0() __builtin_amdgcn_sched_barrier(0)

// MODE 0: out bf16 = rw[m,e0+z] * silu(acc + bias)   (GEMM1 -> hb', rw folded)
// MODE 2: out bf16 = acc                              (GEMM2 -> eo partials)
template <int MODE>
__global__ __launch_bounds__(256, 2) void k_gemm4(
    const __hip_bfloat16* __restrict__ A, int lda, long long strideA,
    const __hip_bfloat16* __restrict__ Bt, int ldb, long long strideB,
    const float* __restrict__ bias, int strideBias,
    const float* __restrict__ rw, int e0,
    void* __restrict__ out, int ldo, long long strideOut, int K)
{
    __shared__ __hip_bfloat16 sA[2][128 * 64];   // 32 KB
    __shared__ __hip_bfloat16 sB[2][128 * 64];   // 32 KB

    const int z = blockIdx.z;
    A  += (size_t)z * (size_t)strideA;
    Bt += (size_t)z * (size_t)strideB;

    const int tid  = threadIdx.x;                // 0..255
    const int lane = tid & 63;
    const int wid  = tid >> 6;                   // 0..3
    const int wr = wid >> 1, wc = wid & 1;       // 2 x 2 waves, 64x64 each
    // grid: x = M-tiles (B-panel sharers consecutive), y = N-tiles
    const int m0 = blockIdx.x * 128, n0 = blockIdx.y * 128;

    // ---- staging: 256 thr x 16B = 4 KB per gload -> 4 gloads per 16 KB tile (32 rows each).
    // dest linear (tid*16); source col pre-swizzled by involution kbyte ^= (row&7)<<4
    const int sr  = tid >> 3;                                        // row 0..31 in chunk
    const int skb = ((((tid & 7) * 16) ^ ((sr & 7) << 4)) >> 1);     // (sr+32j)&7 == sr&7
    const __hip_bfloat16* gA = A  + (size_t)(m0 + sr) * lda + skb;
    const __hip_bfloat16* gB = Bt + (size_t)(n0 + sr) * ldb + skb;
    char* const dA = (char*)&sA[0][0] + tid * 16;
    char* const dB = (char*)&sB[0][0] + tid * 16;

#define STAGE_A(bb, kt) do { \
    const __hip_bfloat16* s_ = gA + (size_t)(kt) * 64; \
    gload_lds16(s_,                     dA + (bb) * 16384); \
    gload_lds16(s_ + (size_t)32 * lda,  dA + (bb) * 16384 + 4096); \
    gload_lds16(s_ + (size_t)64 * lda,  dA + (bb) * 16384 + 8192); \
    gload_lds16(s_ + (size_t)96 * lda,  dA + (bb) * 16384 + 12288); \
} while (0)
#define STAGE_B(bb, kt) do { \
    const __hip_bfloat16* s_ = gB + (size_t)(kt) * 64; \
    gload_lds16(s_,                     dB + (bb) * 16384); \
    gload_lds16(s_ + (size_t)32 * ldb,  dB + (bb) * 16384 + 4096); \
    gload_lds16(s_ + (size_t)64 * ldb,  dB + (bb) * 16384 + 8192); \
    gload_lds16(s_ + (size_t)96 * ldb,  dB + (bb) * 16384 + 12288); \
} while (0)

    // ---- ds_read fragment addressing (swizzled). Wave rows start at wr*64 (A) / wc*64 (B).
    const int fr = lane & 15, kg = lane >> 4;
    const int msk  = (fr & 7) << 4;
    const int kof0 = (kg * 16) ^ msk;
    const int kof1 = (64 + kg * 16) ^ msk;
    const char* rdA = (const char*)&sA[0][0] + wr * 8192 + fr * 128;
    const char* rdB = (const char*)&sB[0][0] + wc * 8192 + fr * 128;

    f32x4  acc[4][4] = {};
    bf16x8 a[4], b[4];

    const int NT = K >> 6;                       // K-tiles of 64 (even, >= 4)

    // ---- prologue: stage tile0 -> buf0, drain, barrier.
    STAGE_A(0, 0); STAGE_B(0, 0);
    VMW0(); BAR(); SCHED0();

    // tile t in buf BB; stages t+1 -> buf BB^1. One barrier + one vmcnt per tile.
#define TILE_S(BB, t) do { \
    ld4(a, rdA + (BB) * 16384, kof0); \
    ld4(b, rdB + (BB) * 16384, kof0); \
    STAGE_A((BB) ^ 1, (t) + 1); STAGE_B((BB) ^ 1, (t) + 1); \
    LGKM0(); SCHED0(); \
    mfma16(a, b, acc); \
    ld4(a, rdA + (BB) * 16384, kof1); \
    ld4(b, rdB + (BB) * 16384, kof1); \
    LGKM0(); SCHED0(); \
    mfma16(a, b, acc); \
    VMW0(); BAR(); SCHED0(); \
} while (0)

    for (int i = 0; i < NT / 2 - 1; ++i) {
        TILE_S(0, 2 * i);
        TILE_S(1, 2 * i + 1);
    }
    TILE_S(0, NT - 2);                           // stages NT-1 -> buf1
    {   // ---- last tile (buf1): pure reads, no stage/barrier needed
        ld4(a, rdA + 16384, kof0);
        ld4(b, rdB + 16384, kof0);
        LGKM0(); SCHED0();
        mfma16(a, b, acc);
        ld4(a, rdA + 16384, kof1);
        ld4(b, rdB + 16384, kof1);
        LGKM0(); SCHED0();
        mfma16(a, b, acc);
    }

    // ---- epilogue. C-frag layout: col = lane&15 (fr), row = kg*4 + j  [m89-verified]
    const int rB = kg * 4;
    if (MODE == 0) {
        __hip_bfloat16* O = (__hip_bfloat16*)out + (size_t)z * (size_t)strideOut;
        const float* bz = bias + (size_t)z * (size_t)strideBias;
#pragma unroll
        for (int mi = 0; mi < 4; ++mi) {
            const int gm = m0 + wr * 64 + mi * 16 + rB;
#pragma unroll
            for (int j = 0; j < 4; ++j) {
                const int row = gm + j;
                const float rwv = rw[(size_t)row * E_EXP + e0 + z];
#pragma unroll
                for (int ni = 0; ni < 4; ++ni) {
                    const int gn = n0 + wc * 64 + ni * 16 + fr;
                    float v = acc[mi][ni][j] + bz[gn];
                    v = v / (1.f + __expf(-v));        // silu
                    O[(size_t)row * ldo + gn] = __float2bfloat16(rwv * v);
                }
            }
        }
    } else {
        __hip_bfloat16* O = (__hip_bfloat16*)out + (size_t)z * (size_t)strideOut;
#pragma unroll
        for (int mi = 0; mi < 4; ++mi) {
            const int gm = m0 + wr * 64 + mi * 16 + rB;
#pragma unroll
            for (int ni = 0; ni < 4; ++ni) {
                const int gn = n0 + wc * 64 + ni * 16 + fr;
#pragma unroll
                for (int j = 0; j < 4; ++j)
                    O[(size_t)(gm + j) * ldo + gn] = __float2bfloat16(acc[mi][ni][j]);
            }
        }
    }
#undef STAGE_A
#undef STAGE_B
#undef TILE_S
}

// -------- combine: x[t,h] += sum_j eo[j][t][h] + sum_j rw[t,e0+j]*b2[e0+j][h].
// (rw already folded into eo via GEMM1's epilogue). eo is bf16. 1 block/token.
__global__ __launch_bounds__(256) void k_combine(
    const __hip_bfloat16* __restrict__ eo, const float* __restrict__ rw,
    const float* __restrict__ b2, float* __restrict__ x, int e0, int g)
{
    const int t = blockIdx.x;
    const int h = threadIdx.x * 4;
    float4 acc = *(const float4*)(x + (size_t)t * H_DIM + h);
    for (int j = 0; j < g; ++j) {
        const float w = rw[(size_t)t * E_EXP + e0 + j];
        const __hip_bfloat16* p = eo + ((size_t)j * T_TOK + t) * H_DIM + h;
        const float4 bz = *(const float4*)(b2 + (size_t)(e0 + j) * H_DIM + h);
        acc.x += __bfloat162float(p[0]) + w * bz.x;
        acc.y += __bfloat162float(p[1]) + w * bz.y;
        acc.z += __bfloat162float(p[2]) + w * bz.z;
        acc.w += __bfloat162float(p[3]) + w * bz.w;
    }
    *(float4*)(x + (size_t)t * H_DIM + h) = acc;
}

extern "C" void kernel_launch(void* const* d_in, const int* in_sizes, int n_in,
                              void* d_out, int out_size, void* d_ws, size_t ws_size,
                              hipStream_t stream)
{
    const float* hidden = (const float*)d_in[0];
    const float* gate_w = (const float*)d_in[1];
    const float* w1     = (const float*)d_in[2];
    const float* b1     = (const float*)d_in[3];
    const float* w2     = (const float*)d_in[4];
    const float* b2     = (const float*)d_in[5];
    const float* ln_w   = (const float*)d_in[6];
    float* x = (float*)d_out;

    // workspace carve
    const size_t w1t_b = (size_t)E_EXP * I_DIM * H_DIM * 2;   // 64 MB
    const size_t w2t_b = (size_t)E_EXP * H_DIM * I_DIM * 2;   // 64 MB
    const size_t tb_b  = (size_t)T_TOK * H_DIM * 2;           //  8 MB
    const size_t rw_b  = (size_t)T_TOK * E_EXP * 4;           // 128 KB
    const size_t hb1_b = (size_t)T_TOK * I_DIM * 2;           // 32 MB per expert
    const size_t eo1_b = (size_t)T_TOK * H_DIM * 2;           //  8 MB per expert (bf16)
    const size_t base_b = w1t_b + w2t_b + tb_b + rw_b;

    // largest expert group that fits
    int g = 0;
    for (int cand = 8; cand >= 1; cand >>= 1)
        if (base_b + (size_t)cand * (hb1_b + eo1_b) <= ws_size) { g = cand; break; }

    char* ws = (char*)d_ws;
    __hip_bfloat16* w1t = (__hip_bfloat16*)ws;  ws += w1t_b;
    __hip_bfloat16* w2t = (__hip_bfloat16*)ws;  ws += w2t_b;
    __hip_bfloat16* tb  = (__hip_bfloat16*)ws;  ws += tb_b;
    float*          rw  = (float*)ws;           ws += rw_b;
    __hip_bfloat16* hb  = (__hip_bfloat16*)ws;
    __hip_bfloat16* eo  = (__hip_bfloat16*)(ws + (size_t)(g > 0 ? g : 1) * hb1_b);

    // x = hidden_states (running residual lives in d_out)
    hipMemcpyAsync(x, hidden, (size_t)T_TOK * H_DIM * 4, hipMemcpyDeviceToDevice, stream);

    if (g == 0) return;  // ws too small (harness has given >= 456 MB so far)

    // bf16 weights in B^T layout: w1t [E][I][H], w2t [E][H][I]
    k_transpose_cvt<<<dim3(I_DIM / 32, H_DIM / 32, E_EXP), 256, 0, stream>>>(w1, w1t, H_DIM, I_DIM);
    k_transpose_cvt<<<dim3(H_DIM / 32, I_DIM / 32, E_EXP), 256, 0, stream>>>(w2, w2t, I_DIM, H_DIM);

    for (int step = 0; step < 2; ++step) {
        k_prep<<<T_TOK, 256, 0, stream>>>(x, ln_w, tb, step);
        k_gate<<<T_TOK / 4, 256, 0, stream>>>(tb, gate_w, rw);

        for (int e0 = 0; e0 < E_EXP; e0 += g) {
            // GEMM1: hb'[z] = rw .* silu(tb @ w1t[e0+z]^T + b1[e0+z]);  M=T, N=I, K=H
            // grid x = M-tiles: consecutive blocks share the w1t column panel.
            k_gemm4<0><<<dim3(T_TOK / 128, I_DIM / 128, g), 256, 0, stream>>>(
                tb, H_DIM, 0,
                w1t + (size_t)e0 * I_DIM * H_DIM, H_DIM, (long long)I_DIM * H_DIM,
                b1 + (size_t)e0 * I_DIM, I_DIM,
                rw, e0,
                hb, I_DIM, (long long)T_TOK * I_DIM, H_DIM);
            // GEMM2: eo[z] = hb'[z] @ w2t[e0+z]^T  (bf16 partials), M=T, N=H, K=I
            k_gemm4<2><<<dim3(T_TOK / 128, H_DIM / 128, g), 256, 0, stream>>>(
                hb, I_DIM, (long long)T_TOK * I_DIM,
                w2t + (size_t)e0 * H_DIM * I_DIM, I_DIM, (long long)H_DIM * I_DIM,
                nullptr, 0,
                nullptr, 0,
                eo, H_DIM, (long long)T_TOK * H_DIM, I_DIM);
            // x += sum_j eo_j + sum_j rw_j*b2_j
            k_combine<<<T_TOK, 256, 0, stream>>>(eo, rw, b2, x, e0, g);
        }
    }
}

// Round 13
// 1433.801 us; speedup vs baseline: 1.1446x; 1.1446x over previous
//
#include <hip/hip_runtime.h>
#include <hip/hip_bf16.h>

// Problem constants (reference: B=2,S=2048 -> T=4096; H=1024, I=4096, E=8, 2 steps)
#define T_TOK 4096
#define H_DIM 1024
#define I_DIM 4096
#define E_EXP 8
#define RMS_EPS_F 1e-6f

using bf16x8 = __attribute__((ext_vector_type(8))) __bf16;
using f32x4  = __attribute__((ext_vector_type(4))) float;

__device__ inline void gload_lds16(const void* g, void* l) {
    __builtin_amdgcn_global_load_lds(
        (const __attribute__((address_space(1))) void*)g,
        (__attribute__((address_space(3))) void*)l,
        16, 0, 0);
}

// -------- transpose + fp32->bf16 convert: in [R][C] -> out [C][R], batched over blockIdx.z
__global__ __launch_bounds__(256) void k_transpose_cvt(
    const float* __restrict__ in, __hip_bfloat16* __restrict__ out, int R, int C)
{
    __shared__ float tile[32][33];
    const size_t mat = (size_t)R * C;
    in  += (size_t)blockIdx.z * mat;
    out += (size_t)blockIdx.z * mat;
    const int c0 = blockIdx.x * 32, r0 = blockIdx.y * 32;
    const int tx = threadIdx.x & 31, ty = threadIdx.x >> 5;   // 32 x 8
#pragma unroll
    for (int dy = 0; dy < 32; dy += 8)
        tile[ty + dy][tx] = in[(size_t)(r0 + ty + dy) * C + (c0 + tx)];
    __syncthreads();
#pragma unroll
    for (int dy = 0; dy < 32; dy += 8)
        out[(size_t)(c0 + ty + dy) * R + (r0 + tx)] = __float2bfloat16(tile[tx][ty + dy]);
}

// -------- token prep: x [T,H] fp32 -> tb [T,H] bf16, optional rmsnorm*ln_w. 1 block/token.
__global__ __launch_bounds__(256) void k_prep(
    const float* __restrict__ x, const float* __restrict__ lnw,
    __hip_bfloat16* __restrict__ tb, int do_norm)
{
    const int t = blockIdx.x;
    const float* row = x + (size_t)t * H_DIM;
    const int base = threadIdx.x * 4;
    float4 v = *(const float4*)(row + base);
    if (do_norm) {
        float ss = v.x*v.x + v.y*v.y + v.z*v.z + v.w*v.w;
#pragma unroll
        for (int off = 32; off > 0; off >>= 1) ss += __shfl_xor(ss, off);
        __shared__ float wsum[4];
        const int w = threadIdx.x >> 6;
        if ((threadIdx.x & 63) == 0) wsum[w] = ss;
        __syncthreads();
        const float tot = wsum[0] + wsum[1] + wsum[2] + wsum[3];
        const float scale = rsqrtf(tot * (1.0f / H_DIM) + RMS_EPS_F);
        float4 g = *(const float4*)(lnw + base);
        v.x *= scale * g.x; v.y *= scale * g.y; v.z *= scale * g.z; v.w *= scale * g.w;
    }
    __hip_bfloat16* o = tb + (size_t)t * H_DIM + base;
    o[0] = __float2bfloat16(v.x); o[1] = __float2bfloat16(v.y);
    o[2] = __float2bfloat16(v.z); o[3] = __float2bfloat16(v.w);
}

// -------- gate: logits = tb @ gate_w^T, softmax over E=8. One wave per token.
__global__ __launch_bounds__(256) void k_gate(
    const __hip_bfloat16* __restrict__ tb, const float* __restrict__ gw,
    float* __restrict__ rw)
{
    const int t = blockIdx.x * 4 + (threadIdx.x >> 6);
    const int lane = threadIdx.x & 63;
    const __hip_bfloat16* row = tb + (size_t)t * H_DIM;
    float acc[E_EXP];
#pragma unroll
    for (int e = 0; e < E_EXP; ++e) acc[e] = 0.f;
    for (int h = lane; h < H_DIM; h += 64) {
        const float xv = __bfloat162float(row[h]);
#pragma unroll
        for (int e = 0; e < E_EXP; ++e) acc[e] += xv * gw[e * H_DIM + h];
    }
#pragma unroll
    for (int e = 0; e < E_EXP; ++e) {
#pragma unroll
        for (int off = 32; off > 0; off >>= 1) acc[e] += __shfl_xor(acc[e], off);
    }
    if (lane == 0) {
        float mx = acc[0];
#pragma unroll
        for (int e = 1; e < E_EXP; ++e) mx = fmaxf(mx, acc[e]);
        float ex[E_EXP], s = 0.f;
#pragma unroll
        for (int e = 0; e < E_EXP; ++e) { ex[e] = __expf(acc[e] - mx); s += ex[e]; }
        const float inv = 1.f / s;
#pragma unroll
        for (int e = 0; e < E_EXP; ++e) rw[(size_t)t * E_EXP + e] = ex[e] * inv;
    }
}

// ======== PERSISTENT 256x256 GEMM, 8 waves (2Mx4N of 128x64), BK=64 dbuf.
// Round-13: R11's K-loop (byte-identical TILE_PIPE ledger, 3x verified) wrapped
// in a per-block tile loop. Grid = 256 blocks (all co-resident, 1/CU); each
// block processes `rounds` tiles in R3's dispatch order (x fastest). Measured
// model from R11: steady S~4750 cyc/K-tile, fixed F~35k cyc/block (boundary:
// epilogue drain + dispatch gap + cold prologue). Persistence removes the
// dispatch gap and OVERLAPS next tile's 12-gload prologue under the epilogue:
//   [final MFMA] BAR -> stage12(next tile) -> epilogue(this tile) -> VMW(4) BAR.
// vmcnt is in-order (m135): stores issued after the 12 loads, so VMW(4)
// guarantees all 12 loads done (over-satisfies T0-ready; in-loop VMW(4)s have
// loads-last ordering so the steady ledger is unchanged).

template<int BB, int MBASE>
__device__ __forceinline__ void ld_a4(bf16x8 (&a)[4], const char* rdA, int kof) {
#pragma unroll
    for (int mi = 0; mi < 4; ++mi)
        a[mi] = *(const bf16x8*)(rdA + BB * 32768 + (MBASE + mi) * 2048 + kof);
}
template<int BB>
__device__ __forceinline__ void ld_b4(bf16x8 (&b)[4], const char* rdB, int kof) {
#pragma unroll
    for (int ni = 0; ni < 4; ++ni)
        b[ni] = *(const bf16x8*)(rdB + BB * 32768 + ni * 2048 + kof);
}
template<int MB>
__device__ __forceinline__ void mfma_cell(const bf16x8 (&a)[4], const bf16x8 (&b)[4],
                                          f32x4 (&acc)[8][4]) {
    __builtin_amdgcn_s_setprio(1);
#pragma unroll
    for (int mi = 0; mi < 4; ++mi)
#pragma unroll
        for (int ni = 0; ni < 4; ++ni)
            acc[MB + mi][ni] = __builtin_amdgcn_mfma_f32_16x16x32_bf16(
                a[mi], b[ni], acc[MB + mi][ni], 0, 0, 0);
    __builtin_amdgcn_s_setprio(0);
}

#define BAR()   __builtin_amdgcn_s_barrier()
#define LGKM0() asm volatile("s_waitcnt lgkmcnt(0)" ::: "memory")
#define VMW(n)  asm volatile("s_waitcnt vmcnt(" #n ")" ::: "memory")
#define SCHED0() __builtin_amdgcn_sched_barrier(0)

// MODE 0: out bf16 = rw[m,e0+z] * silu(acc + bias)   (GEMM1 -> hb', rw folded)
// MODE 2: out bf16 = acc                              (GEMM2 -> eo partials)
template <int MODE>
__global__ __launch_bounds__(512, 2) void k_gemm8p(
    const __hip_bfloat16* __restrict__ A, int lda, long long strideA,
    const __hip_bfloat16* __restrict__ Bt, int ldb, long long strideB,
    const float* __restrict__ bias, int strideBias,
    const float* __restrict__ rw, int e0,
    void* __restrict__ out, int ldo, long long strideOut, int K,
    int gx, int gy, int rounds)
{
    __shared__ __hip_bfloat16 sA[2][2][128 * 64];   // 64 KB
    __shared__ __hip_bfloat16 sB[2][2][128 * 64];   // 64 KB

    const int tid  = threadIdx.x;
    const int lane = tid & 63;
    const int wid  = tid >> 6;
    const int wr = wid >> 2, wc = wid & 3;          // 2 x 4 waves

    // ---- staging geometry: dest linear (tid*16); source col pre-swizzled (involution ^(row&7)<<4)
    const int sr  = tid >> 3;
    const int skb = ((((tid & 7) * 16) ^ ((sr & 7) << 4)) >> 1);
    char* const dA = (char*)&sA[0][0][0] + tid * 16;
    char* const dB = (char*)&sB[0][0][0] + tid * 16;

    // ---- ds_read fragment addressing (swizzled)
    const int fr = lane & 15, kg = lane >> 4;
    const int msk  = (fr & 7) << 4;
    const int kof0 = (kg * 16) ^ msk;
    const int kof1 = (64 + kg * 16) ^ msk;
    const char* rdA = (const char*)&sA[0][wr][0] + fr * 128;
    const char* rdB = (const char*)&sB[0][wc >> 1][0] + (wc & 1) * 8192 + fr * 128;

    const int NT = K >> 6;                          // K-tiles of 64 (even, >= 4)
    const int rB = kg * 4;

    const __hip_bfloat16* gA;
    const __hip_bfloat16* gB;
    int m0, n0, zz;

#define SET_TILE(r) do { \
    const int idx_ = blockIdx.x + (r) * gridDim.x; \
    const int x_ = idx_ % gx; \
    const int t2_ = idx_ / gx; \
    const int y_ = t2_ % gy; \
    zz = t2_ / gy; \
    m0 = y_ * 256; n0 = x_ * 256; \
    gA = A + (size_t)zz * (size_t)strideA + (size_t)(m0 + sr) * lda + skb; \
    gB = Bt + (size_t)zz * (size_t)strideB + (size_t)(n0 + sr) * ldb + skb; \
} while (0)

#define STAGE_A(bb, hh, kt) do { \
    const __hip_bfloat16* s_ = gA + (size_t)(hh) * 128 * lda + (size_t)(kt) * 64; \
    gload_lds16(s_,                     dA + (bb) * 32768 + (hh) * 16384); \
    gload_lds16(s_ + (size_t)64 * lda,  dA + (bb) * 32768 + (hh) * 16384 + 8192); \
} while (0)
#define STAGE_B(bb, hh, kt) do { \
    const __hip_bfloat16* s_ = gB + (size_t)(hh) * 128 * ldb + (size_t)(kt) * 64; \
    gload_lds16(s_,                     dB + (bb) * 32768 + (hh) * 16384); \
    gload_lds16(s_ + (size_t)64 * ldb,  dB + (bb) * 32768 + (hh) * 16384 + 8192); \
} while (0)

// prologue of a tile: T0 (B,A) + T1 (B) = 12 gloads
#define STAGE12() do { \
    STAGE_B(0, 0, 0); STAGE_B(0, 1, 0); \
    STAGE_A(0, 0, 0); STAGE_A(0, 1, 0); \
    STAGE_B(1, 0, 1); STAGE_B(1, 1, 1); \
} while (0)

// R11's pipelined K-tile (buf BB, tile t): stages A(t+1)->BB^1, B(t+2)->BB.
#define TILE_PIPE(BB, t) do { \
    ld_a4<BB, 0>(a, rdA, kof0); \
    ld_b4<BB>(b, rdB, kof0); \
    STAGE_A((BB) ^ 1, 0, (t) + 1); \
    LGKM0(); SCHED0(); \
    ld_a4<BB, 4>(a2, rdA, kof0); \
    SCHED0(); \
    mfma_cell<0>(a, b, acc); \
    STAGE_A((BB) ^ 1, 1, (t) + 1); \
    LGKM0(); SCHED0(); \
    ld_a4<BB, 4>(a2n, rdA, kof1); \
    ld_b4<BB>(bn, rdB, kof1); \
    SCHED0(); \
    mfma_cell<4>(a2, b, acc); \
    BAR(); \
    LGKM0(); SCHED0(); \
    ld_a4<BB, 0>(a, rdA, kof1); \
    SCHED0(); \
    STAGE_B(BB, 0, (t) + 2); \
    mfma_cell<4>(a2n, bn, acc); \
    LGKM0(); SCHED0(); \
    STAGE_B(BB, 1, (t) + 2); \
    mfma_cell<0>(a, bn, acc); \
    VMW(4); BAR(); SCHED0(); \
} while (0)

    f32x4  acc[8][4];
    bf16x8 a[4], b[4], a2[4], a2n[4], bn[4];

    SET_TILE(0);
    STAGE12();

#pragma unroll 1
    for (int r = 0; r < rounds; ++r) {
        VMW(4); BAR(); SCHED0();
#pragma unroll
        for (int mi = 0; mi < 8; ++mi)
#pragma unroll
            for (int ni = 0; ni < 4; ++ni)
#pragma unroll
                for (int q = 0; q < 4; ++q) acc[mi][ni][q] = 0.f;

        for (int i = 0; i < NT / 2 - 1; ++i) {
            TILE_PIPE(0, 2 * i);
            TILE_PIPE(1, 2 * i + 1);
        }
        // ---- tail: tile NT-2 (buf0; stage A(NT-1)->buf1; drain), tile NT-1 (buf1; pure reads)
        ld_a4<0, 0>(a, rdA, kof0);
        ld_b4<0>(b, rdB, kof0);
        STAGE_A(1, 0, NT - 1);
        LGKM0(); SCHED0();
        ld_a4<0, 4>(a2, rdA, kof0);
        SCHED0();
        mfma_cell<0>(a, b, acc);
        STAGE_A(1, 1, NT - 1);
        LGKM0(); SCHED0();
        ld_a4<0, 4>(a2n, rdA, kof1);
        ld_b4<0>(bn, rdB, kof1);
        SCHED0();
        mfma_cell<4>(a2, b, acc);
        BAR();
        LGKM0(); SCHED0();
        ld_a4<0, 0>(a, rdA, kof1);
        SCHED0();
        mfma_cell<4>(a2n, bn, acc);
        LGKM0(); SCHED0();
        mfma_cell<0>(a, bn, acc);
        VMW(0); BAR(); SCHED0();
        // tile NT-1 (buf1): nothing writes LDS after the drain
        ld_a4<1, 0>(a, rdA, kof0);
        ld_b4<1>(b, rdB, kof0);
        LGKM0(); SCHED0();
        ld_a4<1, 4>(a2, rdA, kof0);
        SCHED0();
        mfma_cell<0>(a, b, acc);
        LGKM0(); SCHED0();
        ld_a4<1, 4>(a2n, rdA, kof1);
        ld_b4<1>(bn, rdB, kof1);
        SCHED0();
        mfma_cell<4>(a2, b, acc);
        LGKM0(); SCHED0();
        ld_a4<1, 0>(a, rdA, kof1);
        SCHED0();
        mfma_cell<4>(a2n, bn, acc);
        LGKM0(); SCHED0();
        mfma_cell<0>(a, bn, acc);

        // ---- tile boundary: all waves done reading LDS -> barrier, then
        // stage NEXT tile's prologue (12 gloads) BEFORE the epilogue so the
        // epilogue's compute+stores hide the cold-fetch latency.
        BAR();
        const int em0 = m0, en0 = n0, ez = zz;
        if (r + 1 < rounds) { SET_TILE(r + 1); STAGE12(); }

        // ---- epilogue for tile (em0, en0, ez).
        // C-frag layout: col = lane&15 (fr), row = kg*4 + j  [m89-verified]
        if (MODE == 0) {
            __hip_bfloat16* O = (__hip_bfloat16*)out + (size_t)ez * (size_t)strideOut;
            const float* bz = bias + (size_t)ez * (size_t)strideBias;
#pragma unroll
            for (int mi = 0; mi < 8; ++mi) {
                const int gm = em0 + wr * 128 + mi * 16 + rB;
#pragma unroll
                for (int j = 0; j < 4; ++j) {
                    const int row = gm + j;
                    const float rwv = rw[(size_t)row * E_EXP + e0 + ez];
#pragma unroll
                    for (int ni = 0; ni < 4; ++ni) {
                        const int gn = en0 + wc * 64 + ni * 16 + fr;
                        float v = acc[mi][ni][j] + bz[gn];
                        v = v / (1.f + __expf(-v));        // silu
                        O[(size_t)row * ldo + gn] = __float2bfloat16(rwv * v);
                    }
                }
            }
        } else {
            __hip_bfloat16* O = (__hip_bfloat16*)out + (size_t)ez * (size_t)strideOut;
#pragma unroll
            for (int mi = 0; mi < 8; ++mi) {
                const int gm = em0 + wr * 128 + mi * 16 + rB;
#pragma unroll
                for (int ni = 0; ni < 4; ++ni) {
                    const int gn = en0 + wc * 64 + ni * 16 + fr;
#pragma unroll
                    for (int j = 0; j < 4; ++j)
                        O[(size_t)(gm + j) * ldo + gn] = __float2bfloat16(acc[mi][ni][j]);
                }
            }
        }
    }
#undef SET_TILE
#undef STAGE_A
#undef STAGE_B
#undef STAGE12
#undef TILE_PIPE
}

// -------- combine: x[t,h] += sum_j eo[j][t][h] + sum_j rw[t,e0+j]*b2[e0+j][h].
// (rw already folded into eo via GEMM1's epilogue). eo is bf16. 1 block/token.
__global__ __launch_bounds__(256) void k_combine(
    const __hip_bfloat16* __restrict__ eo, const float* __restrict__ rw,
    const float* __restrict__ b2, float* __restrict__ x, int e0, int g)
{
    const int t = blockIdx.x;
    const int h = threadIdx.x * 4;
    float4 acc = *(const float4*)(x + (size_t)t * H_DIM + h);
    for (int j = 0; j < g; ++j) {
        const float w = rw[(size_t)t * E_EXP + e0 + j];
        const __hip_bfloat16* p = eo + ((size_t)j * T_TOK + t) * H_DIM + h;
        const float4 bz = *(const float4*)(b2 + (size_t)(e0 + j) * H_DIM + h);
        acc.x += __bfloat162float(p[0]) + w * bz.x;
        acc.y += __bfloat162float(p[1]) + w * bz.y;
        acc.z += __bfloat162float(p[2]) + w * bz.z;
        acc.w += __bfloat162float(p[3]) + w * bz.w;
    }
    *(float4*)(x + (size_t)t * H_DIM + h) = acc;
}

extern "C" void kernel_launch(void* const* d_in, const int* in_sizes, int n_in,
                              void* d_out, int out_size, void* d_ws, size_t ws_size,
                              hipStream_t stream)
{
    const float* hidden = (const float*)d_in[0];
    const float* gate_w = (const float*)d_in[1];
    const float* w1     = (const float*)d_in[2];
    const float* b1     = (const float*)d_in[3];
    const float* w2     = (const float*)d_in[4];
    const float* b2     = (const float*)d_in[5];
    const float* ln_w   = (const float*)d_in[6];
    float* x = (float*)d_out;

    // workspace carve
    const size_t w1t_b = (size_t)E_EXP * I_DIM * H_DIM * 2;   // 64 MB
    const size_t w2t_b = (size_t)E_EXP * H_DIM * I_DIM * 2;   // 64 MB
    const size_t tb_b  = (size_t)T_TOK * H_DIM * 2;           //  8 MB
    const size_t rw_b  = (size_t)T_TOK * E_EXP * 4;           // 128 KB
    const size_t hb1_b = (size_t)T_TOK * I_DIM * 2;           // 32 MB per expert
    const size_t eo1_b = (size_t)T_TOK * H_DIM * 2;           //  8 MB per expert (bf16)
    const size_t base_b = w1t_b + w2t_b + tb_b + rw_b;

    // largest expert group that fits
    int g = 0;
    for (int cand = 8; cand >= 1; cand >>= 1)
        if (base_b + (size_t)cand * (hb1_b + eo1_b) <= ws_size) { g = cand; break; }

    char* ws = (char*)d_ws;
    __hip_bfloat16* w1t = (__hip_bfloat16*)ws;  ws += w1t_b;
    __hip_bfloat16* w2t = (__hip_bfloat16*)ws;  ws += w2t_b;
    __hip_bfloat16* tb  = (__hip_bfloat16*)ws;  ws += tb_b;
    float*          rw  = (float*)ws;           ws += rw_b;
    __hip_bfloat16* hb  = (__hip_bfloat16*)ws;
    __hip_bfloat16* eo  = (__hip_bfloat16*)(ws + (size_t)(g > 0 ? g : 1) * hb1_b);

    // x = hidden_states (running residual lives in d_out)
    hipMemcpyAsync(x, hidden, (size_t)T_TOK * H_DIM * 4, hipMemcpyDeviceToDevice, stream);

    if (g == 0) return;  // ws too small (harness has given >= 456 MB so far)

    // bf16 weights in B^T layout: w1t [E][I][H], w2t [E][H][I]
    k_transpose_cvt<<<dim3(I_DIM / 32, H_DIM / 32, E_EXP), 256, 0, stream>>>(w1, w1t, H_DIM, I_DIM);
    k_transpose_cvt<<<dim3(H_DIM / 32, I_DIM / 32, E_EXP), 256, 0, stream>>>(w2, w2t, I_DIM, H_DIM);

    for (int step = 0; step < 2; ++step) {
        k_prep<<<T_TOK, 256, 0, stream>>>(x, ln_w, tb, step);
        k_gate<<<T_TOK / 4, 256, 0, stream>>>(tb, gate_w, rw);

        for (int e0 = 0; e0 < E_EXP; e0 += g) {
            // GEMM1: hb'[z] = rw .* silu(tb @ w1t[e0+z]^T + b1[e0+z]);  M=T, N=I, K=H
            const int gx1 = I_DIM / 256, gy1 = T_TOK / 256;
            const int tiles1 = gx1 * gy1 * g;
            const int grid1  = tiles1 < 256 ? tiles1 : 256;
            k_gemm8p<0><<<grid1, 512, 0, stream>>>(
                tb, H_DIM, 0,
                w1t + (size_t)e0 * I_DIM * H_DIM, H_DIM, (long long)I_DIM * H_DIM,
                b1 + (size_t)e0 * I_DIM, I_DIM,
                rw, e0,
                hb, I_DIM, (long long)T_TOK * I_DIM, H_DIM,
                gx1, gy1, tiles1 / grid1);
            // GEMM2: eo[z] = hb'[z] @ w2t[e0+z]^T  (bf16 partials), M=T, N=H, K=I
            const int gx2 = H_DIM / 256, gy2 = T_TOK / 256;
            const int tiles2 = gx2 * gy2 * g;
            const int grid2  = tiles2 < 256 ? tiles2 : 256;
            k_gemm8p<2><<<grid2, 512, 0, stream>>>(
                hb, I_DIM, (long long)T_TOK * I_DIM,
                w2t + (size_t)e0 * H_DIM * I_DIM, I_DIM, (long long)H_DIM * I_DIM,
                nullptr, 0,
                nullptr, 0,
                eo, H_DIM, (long long)T_TOK * H_DIM, I_DIM,
                gx2, gy2, tiles2 / grid2);
            // x += sum_j eo_j + sum_j rw_j*b2_j
            k_combine<<<T_TOK, 256, 0, stream>>>(eo, rw, b2, x, e0, g);
        }
    }
}